// Round 1
// baseline (482.113 us; speedup 1.0000x reference)
//
#include <hip/hip_runtime.h>

// Problem constants (from reference): feats [B=8, C=256, H=128, W=256] f32,
// labels [8,128,256] int32 in [0,19). Outputs: means [19,256] then norm_means [19].
#define NCLS   19
#define NCH    256
#define HW     (128 * 256)        // 32768
#define NB     8
#define NPIX   (NB * HW)          // 262144
#define CHUNK  512                // pixels per block-chunk (divides HW)
#define NCHUNKS (NPIX / CHUNK)    // 512
#define SUMS   (NCLS * NCH)       // 4864
#define NORM_OFF SUMS             // 4864..4882: per-class norm sums
#define CNT_OFF  (SUMS + NCLS)    // 4883..4901: per-class counts
#define PART   (SUMS + 2 * NCLS)  // 4902 floats per partial slot

__global__ __launch_bounds__(256) void accum_kernel(
    const float* __restrict__ feats, const int* __restrict__ labels,
    float* __restrict__ partials, int nblocks)
{
    __shared__ float lds[PART];   // sums stored as [c*19 + k] for bank spread
    const int t = threadIdx.x;
    for (int j = t; j < PART; j += 256) lds[j] = 0.f;
    __syncthreads();

    for (int chunk = blockIdx.x; chunk < NCHUNKS; chunk += nblocks) {
        const int p0 = chunk * CHUNK;          // chunk stays within one image b
        const int b  = p0 / HW;
        const int hw = (p0 % HW) + 2 * t;      // 2 pixels per thread (float2)
        const int p  = p0 + 2 * t;
        const int k0 = labels[p];
        const int k1 = labels[p + 1];
        const float* fp = feats + (size_t)b * ((size_t)NCH * HW) + hw;
        float sq0 = 0.f, sq1 = 0.f;
        #pragma unroll 4
        for (int c = 0; c < NCH; ++c) {
            const float2 v = *reinterpret_cast<const float2*>(fp + (size_t)c * HW);
            atomicAdd(&lds[c * 19 + k0], v.x);
            atomicAdd(&lds[c * 19 + k1], v.y);
            sq0 += v.x * v.x;
            sq1 += v.y * v.y;
        }
        atomicAdd(&lds[NORM_OFF + k0], sqrtf(sq0));
        atomicAdd(&lds[NORM_OFF + k1], sqrtf(sq1));
        atomicAdd(&lds[CNT_OFF + k0], 1.f);
        atomicAdd(&lds[CNT_OFF + k1], 1.f);
    }
    __syncthreads();

    // Flush partials in OUTPUT layout (j<4864 -> [k][c]) so finalize is coalesced.
    float* outp = partials + (size_t)blockIdx.x * PART;
    for (int j = t; j < PART; j += 256) {
        float v;
        if (j < SUMS) v = lds[(j & 255) * 19 + (j >> 8)];  // k=j>>8, c=j&255
        else          v = lds[j];
        outp[j] = v;
    }
}

__global__ __launch_bounds__(256) void finalize_kernel(
    const float* __restrict__ partials, float* __restrict__ outbuf, int nblocks)
{
    const int o = blockIdx.x * blockDim.x + threadIdx.x;
    if (o >= SUMS + NCLS) return;              // 4883 outputs
    const int k = (o < SUMS) ? (o >> 8) : (o - SUMS);
    float s = 0.f, cnt = 0.f;
    for (int g = 0; g < nblocks; ++g) {
        s   += partials[(size_t)g * PART + o];
        cnt += partials[(size_t)g * PART + CNT_OFF + k];
    }
    // ref: where(count>0, sum/max(count,1), 0)
    outbuf[o] = (cnt > 0.f) ? s / fmaxf(cnt, 1.f) : 0.f;
}

extern "C" void kernel_launch(void* const* d_in, const int* in_sizes, int n_in,
                              void* d_out, int out_size, void* d_ws, size_t ws_size,
                              hipStream_t stream) {
    const float* feats  = (const float*)d_in[0];
    const int*   labels = (const int*)d_in[1];
    float* out      = (float*)d_out;
    float* partials = (float*)d_ws;

    int G = (int)(ws_size / (PART * sizeof(float)));
    if (G > NCHUNKS) G = NCHUNKS;
    if (G > 512) G = 512;
    if (G < 1) G = 1;

    accum_kernel<<<G, 256, 0, stream>>>(feats, labels, partials, G);
    finalize_kernel<<<(SUMS + NCLS + 255) / 256, 256, 0, stream>>>(partials, out, G);
}

// Round 2
// 75.018 us; speedup vs baseline: 6.4266x; 6.4266x over previous
//
#include <hip/hip_runtime.h>

// feats [B=8, C=256, H=128, W=256] f32; labels [8,128,256] int32 in [0,19)
// out: means [19][256] then norm_means [19]  (4883 floats)
#define NCLS 19
#define NCH  256
#define HW   (128 * 256)
#define NB   8
#define NPIX (NB * HW)          // 262144
#define P    32                 // pixels per tile
#define NT   (NPIX / P)         // 8192 tiles
#define PAD  33                 // odd pad -> bank = (c+p)&31, conflict-free
#define SUMS (NCLS * NCH)       // 4864
#define WS_NORM 4864
#define WS_CNT  4883
#define WS_TOT  4902

__global__ __launch_bounds__(256) void accum_kernel(
    const float* __restrict__ feats, const int* __restrict__ labels,
    float* __restrict__ ws, int nblocks)
{
    __shared__ float tile[NCH * PAD];   // [c][p] padded
    __shared__ float accA[SUMS];        // even pixels  (exclusive slot per thread)
    __shared__ float accB[SUMS];        // odd pixels
    __shared__ float accN[NCLS];
    __shared__ float accC[NCLS];
    __shared__ float sqred[8 * P];      // [g][p] partial squared-norms
    __shared__ int   lab_s[P];

    const int t = threadIdx.x;
    for (int j = t; j < SUMS; j += 256) { accA[j] = 0.f; accB[j] = 0.f; }
    if (t < NCLS) { accN[t] = 0.f; accC[t] = 0.f; }

    for (int tl = blockIdx.x; tl < NT; tl += nblocks) {
        const int p0  = tl * P;         // tile stays within one image (HW%P==0)
        const int b   = p0 / HW;
        const int hw0 = p0 % HW;
        const float* fb = feats + (size_t)b * NCH * HW + hw0;

        __syncthreads();                // (A) prev tile fully consumed
        // STAGE: 8 float4 global loads/thread -> padded LDS tile
        {
            const int j4 = (t & 7) * 4;
            const int cb = t >> 3;
            #pragma unroll
            for (int i = 0; i < 8; ++i) {
                const int c = i * 32 + cb;
                const float4 v = *reinterpret_cast<const float4*>(fb + (size_t)c * HW + j4);
                tile[c * PAD + j4    ] = v.x;
                tile[c * PAD + j4 + 1] = v.y;
                tile[c * PAD + j4 + 2] = v.z;
                tile[c * PAD + j4 + 3] = v.w;
            }
            if (t < P) lab_s[t] = labels[p0 + t];
        }
        __syncthreads();                // (B) tile + labels ready

        // SQPART: 8 groups x 32 pixels, conflict-free column reads
        {
            const int g = t >> 5, p = t & 31;
            float s = 0.f;
            #pragma unroll
            for (int i = 0; i < 32; ++i) {
                const float x = tile[(g * 32 + i) * PAD + p];
                s += x * x;
            }
            sqred[g * 32 + p] = s;
        }
        // ACCUM: thread t owns channel c=t; exclusive slots -> NO atomics
        {
            float v[P];
            #pragma unroll
            for (int p = 0; p < P; ++p) v[p] = tile[t * PAD + p];
            #pragma unroll
            for (int p = 0; p < P; p += 2) {
                const int k0 = lab_s[p];       // wave-uniform broadcast reads
                const int k1 = lab_s[p + 1];
                accA[k0 * NCH + t] += v[p];    // two copies -> two independent
                accB[k1 * NCH + t] += v[p + 1];// RMW chains interleave
            }
        }
        __syncthreads();                // (C) sqred ready
        if (t < P) {
            float s = 0.f;
            #pragma unroll
            for (int g = 0; g < 8; ++g) s += sqred[g * 32 + t];
            const int k = lab_s[t];
            unsafeAtomicAdd(&accN[k], sqrtf(s));   // 32 lanes, native ds_add_f32
            unsafeAtomicAdd(&accC[k], 1.f);
        }
    }

    __syncthreads();
    // Flush block partials into global accumulator (zeroed by memset)
    for (int j = t; j < SUMS; j += 256)
        unsafeAtomicAdd(&ws[j], accA[j] + accB[j]);
    if (t < NCLS) {
        unsafeAtomicAdd(&ws[WS_NORM + t], accN[t]);
        unsafeAtomicAdd(&ws[WS_CNT + t], accC[t]);
    }
}

__global__ __launch_bounds__(256) void finalize_kernel(
    const float* __restrict__ ws, float* __restrict__ out)
{
    const int o = blockIdx.x * blockDim.x + threadIdx.x;
    if (o >= SUMS + NCLS) return;
    const int k = (o < SUMS) ? (o >> 8) : (o - SUMS);
    const float cnt = ws[WS_CNT + k];
    const float s   = (o < SUMS) ? ws[o] : ws[WS_NORM + (o - SUMS)];
    out[o] = (cnt > 0.f) ? s / fmaxf(cnt, 1.f) : 0.f;
}

extern "C" void kernel_launch(void* const* d_in, const int* in_sizes, int n_in,
                              void* d_out, int out_size, void* d_ws, size_t ws_size,
                              hipStream_t stream) {
    const float* feats  = (const float*)d_in[0];
    const int*   labels = (const int*)d_in[1];
    float* out = (float*)d_out;
    float* ws  = (float*)d_ws;

    hipMemsetAsync(ws, 0, WS_TOT * sizeof(float), stream);

    const int G = 512;   // 2 blocks/CU (73.5 KB LDS each), 16 tiles/block
    accum_kernel<<<G, 256, 0, stream>>>(feats, labels, ws, G);
    finalize_kernel<<<(SUMS + NCLS + 255) / 256, 256, 0, stream>>>(ws, out);
}